// Round 6
// baseline (219.368 us; speedup 1.0000x reference)
//
#include <hip/hip_runtime.h>
#include <math.h>

#define B_ 128
#define E_ 512
#define C_ 128
#define H_ 8
#define D_ 64
#define BEC_ ((size_t)B_ * E_ * C_)

typedef __attribute__((ext_vector_type(8))) __bf16 bf16x8;
typedef __attribute__((ext_vector_type(4))) float f32x4;

__device__ __forceinline__ ushort f2bf(float f) {
    unsigned u = __float_as_uint(f);
    unsigned r = u + 0x7fffu + ((u >> 16) & 1u);
    return (ushort)(r >> 16);
}
__device__ __forceinline__ float bf2f(ushort h) {
    return __uint_as_float(((unsigned)h) << 16);
}
__device__ __forceinline__ void split_bf(float f, ushort& hi, ushort& lo) {
    hi = f2bf(f);
    lo = f2bf(f - bf2f(hi));
}
__device__ __forceinline__ float selu_f(float x) {
    const float alpha = 1.6732632423543772f;
    const float scale = 1.0507009873554805f;
    return x > 0.0f ? scale * x : scale * alpha * expm1f(x);
}
// async global->LDS, 16B/lane; LDS dest wave-uniform base + lane*16
__device__ __forceinline__ void gll16(const void* g, void* l) {
    __builtin_amdgcn_global_load_lds(
        (const __attribute__((address_space(1))) void*)g,
        (__attribute__((address_space(3))) void*)l, 16, 0, 0);
}

// ---------------------------------------------------------------------------
// knn_mask dtype sniff (bool bytes -> 2688 nonzero in 16KB, int32 -> 672)
// ---------------------------------------------------------------------------
__global__ void detect_mask_kernel(const unsigned char* __restrict__ m,
                                   int* __restrict__ flag) {
    __shared__ int cnt;
    if (threadIdx.x == 0) cnt = 0;
    __syncthreads();
    int local = 0;
    for (int i = threadIdx.x; i < C_ * C_; i += blockDim.x) local += (m[i] != 0);
    atomicAdd(&cnt, local);
    __syncthreads();
    if (threadIdx.x == 0) *flag = (cnt > 1600) ? 1 : 0;
}

// ---------------------------------------------------------------------------
// combT[h][j][i] = mask(i,j) ? attn_bias[i][j] + centered dir bias(i,j) : -inf
// TRANSPOSED store so the attention kernel loads 4 consecutive i as float4.
// ---------------------------------------------------------------------------
__global__ __launch_bounds__(128) void bias_prep_kernel(
    const float* __restrict__ dir_vec, const float* __restrict__ attn_bias,
    const float* __restrict__ disp, const unsigned char* __restrict__ maskb,
    const int* __restrict__ flag, float* __restrict__ combT)
{
    const int i = blockIdx.x, h = blockIdx.y, j = threadIdx.x;
    __shared__ float red[128];

    float dv = dir_vec[h * C_ + j];
    red[j] = dv * dv;
    __syncthreads();
    for (int s = 64; s > 0; s >>= 1) {
        if (j < s) red[j] += red[j + s];
        __syncthreads();
    }
    const float nrm = fmaxf(sqrtf(red[0]), 1e-12f);
    __syncthreads();

    const float dvn_j = dir_vec[h * C_ + j] / nrm;
    const float dvn_i = dir_vec[h * C_ + i] / nrm;
    const float third = 1.0f / 3.0f;
    const float dm_ij = (disp[(i * C_ + j) * 3 + 0] + disp[(i * C_ + j) * 3 + 1] +
                         disp[(i * C_ + j) * 3 + 2]) * third;
    const float dm_ji = (disp[(j * C_ + i) * 3 + 0] + disp[(j * C_ + i) * 3 + 1] +
                         disp[(j * C_ + i) * 3 + 2]) * third;
    const float db = 0.5f * (dm_ij * dvn_j - dm_ji * dvn_i);

    red[j] = db;
    __syncthreads();
    for (int s = 64; s > 0; s >>= 1) {
        if (j < s) red[j] += red[j + s];
        __syncthreads();
    }
    const float rowmean = red[0] * (1.0f / 128.0f);

    const bool mk = (*flag) ? (maskb[i * C_ + j] != 0)
                            : (((const int*)maskb)[i * C_ + j] != 0);
    combT[((size_t)h * C_ + j) * C_ + i] =
        mk ? (attn_bias[i * C_ + j] + db - rowmean) : -INFINITY;
}

// ---------------------------------------------------------------------------
// Split the 4 weight matrices [E][E] fp32 -> hi/lo bf16 (layout preserved).
// ---------------------------------------------------------------------------
__global__ __launch_bounds__(256) void wsplit_kernel(
    const float* __restrict__ w0, const float* __restrict__ w1,
    const float* __restrict__ w2, const float* __restrict__ w3,
    ushort* __restrict__ wh, ushort* __restrict__ wl)
{
    const int s = blockIdx.y;
    const float* __restrict__ w = (s == 0) ? w0 : (s == 1) ? w1 : (s == 2) ? w2 : w3;
    const size_t base = (size_t)s * E_ * E_;
    const size_t i0 = ((size_t)blockIdx.x * 256 + threadIdx.x) * 8;
    const float4 f0 = *(const float4*)&w[i0];
    const float4 f1 = *(const float4*)&w[i0 + 4];
    const float ff[8] = {f0.x, f0.y, f0.z, f0.w, f1.x, f1.y, f1.z, f1.w};
    union { ushort u[8]; uint4 v; } hu, lu;
#pragma unroll
    for (int j = 0; j < 8; ++j) split_bf(ff[j], hu.u[j], lu.u[j]);
    *(uint4*)&wh[base + i0] = hu.v;
    *(uint4*)&wl[base + i0] = lu.v;
}

// ---------------------------------------------------------------------------
// x [B][E][C] fp32 -> xT hi/lo bf16 [B][C][E]  (transpose + split)
// ---------------------------------------------------------------------------
__global__ __launch_bounds__(256) void xsplit_kernel(
    const float* __restrict__ x, ushort* __restrict__ xh, ushort* __restrict__ xl)
{
    const int b = blockIdx.y, e0 = blockIdx.x * 64;
    __shared__ float ts[64][132];
    const int tid = threadIdx.x;
    const float* __restrict__ xb = x + ((size_t)b * E_ + e0) * C_;
#pragma unroll
    for (int r = 0; r < 8; ++r) {
        const int idx = tid + r * 256;
        const int e = idx >> 5, c4 = idx & 31;
        *(float4*)&ts[e][c4 * 4] = *(const float4*)&xb[(size_t)e * C_ + c4 * 4];
    }
    __syncthreads();
    const int lc = tid >> 3;
    const int l8 = (tid & 7) * 8;
#pragma unroll
    for (int p = 0; p < 4; ++p) {
        const int c = p * 32 + lc;
        union { ushort u[8]; uint4 v; } hu, lu;
#pragma unroll
        for (int j = 0; j < 8; ++j) split_bf(ts[l8 + j][c], hu.u[j], lu.u[j]);
        const size_t rb = ((size_t)b * C_ + c) * E_ + e0 + l8;
        *(uint4*)&xh[rb] = hu.v;
        *(uint4*)&xl[rb] = lu.v;
    }
}

// ---------------------------------------------------------------------------
// Split-bf16 MFMA GEMM, 128x128 tile, BK=64, 4 waves x 4x4 frags, 3 terms.
// LDS tiles [128][64] bf16 are XOR-swizzled (T2): linear gll16 dest, global
// source chunk ^= row&7, frag-read byte col ^= (row&7)<<4.  Involution:
// LDS chunk c holds global chunk c^(r&7); reader of global c_g reads LDS
// c_g^(r&7) -> identity. Frag read spreads 16 lanes over 8 bank-quads
// (2-way = free) instead of 16-way same-bank.
// MODE 0 (qkv): z=0 q -> TRANSPOSED split store qT[b][c][E]
//               z=1 k -> TRANSPOSED split store kT[b][c][E]
//               z=2 v -> natural hi-only store v[b][E][C]
// MODE 1 (out): natural fp32 selu store to d_out.
// ---------------------------------------------------------------------------
template<int MODE>
__global__ __launch_bounds__(256, 2) void gemm_kernel(
    const ushort* __restrict__ Wh0, const ushort* __restrict__ Wh1,
    const ushort* __restrict__ Wh2, const ushort* __restrict__ Wl0,
    const ushort* __restrict__ Wl1, const ushort* __restrict__ Wl2,
    const ushort* __restrict__ Bh, const ushort* __restrict__ Bl,
    ushort* __restrict__ qh, ushort* __restrict__ ql,
    ushort* __restrict__ kh, ushort* __restrict__ kl,
    ushort* __restrict__ vhp, float* __restrict__ fout)
{
    const int z = (MODE == 0) ? blockIdx.z : 0;
    const ushort* __restrict__ wh = (z == 0) ? Wh0 : (z == 1) ? Wh1 : Wh2;
    const ushort* __restrict__ wl = (z == 0) ? Wl0 : (z == 1) ? Wl1 : Wl2;
    const bool trans = (MODE == 0) && (z < 2);
    const int b = blockIdx.y;
    const int o0 = blockIdx.x * 128;

    __shared__ ushort sm[4 * 8192];   // Whi | Wlo | Xhi | Xlo, each [128][64]

    const int tid = threadIdx.x;
    const int wid = tid >> 6, lane = tid & 63;
    const int wr64 = (wid >> 1) * 64, wc64 = (wid & 1) * 64;
    const int w4 = wid * 4;
    const int srow = lane >> 3;                       // row&7 within inst block
    const size_t gco = (size_t)((lane & 7) ^ srow) * 16;   // pre-swizzled source

    const char* __restrict__ bhp = (const char*)(Bh + (size_t)b * C_ * E_);
    const char* __restrict__ blp = (const char*)(Bl + (size_t)b * C_ * E_);
    const char* __restrict__ whp = (const char*)wh;
    const char* __restrict__ wlp = (const char*)wl;

    const char* __restrict__ smb = (const char*)sm;
    const int aoffB = trans ? 32768 : 0;     // A-frags from X tile if trans
    const int boffB = trans ? 0 : 32768;

    f32x4 acc[4][4];
#pragma unroll
    for (int m = 0; m < 4; ++m)
#pragma unroll
        for (int n = 0; n < 4; ++n) acc[m][n] = (f32x4)0.0f;

    const int l15 = lane & 15;

    for (int k0 = 0; k0 < E_; k0 += 64) {
#pragma unroll
        for (int t = 0; t < 4; ++t) {
            const int inst = w4 + t;
            const int r = inst * 8 + srow;
            const size_t arow = ((size_t)(o0 + r) * E_ + k0) * 2 + gco;
            const size_t brow = ((size_t)r * E_ + k0) * 2 + gco;
            gll16(whp + arow, &sm[inst * 512]);
            gll16(wlp + arow, &sm[8192 + inst * 512]);
            gll16(bhp + brow, &sm[16384 + inst * 512]);
            gll16(blp + brow, &sm[24576 + inst * 512]);
        }
        __syncthreads();
#pragma unroll
        for (int kk = 0; kk < 2; ++kk) {
            const int kbyte = kk * 64 + (lane >> 4) * 16;
            bf16x8 ah[4], al[4], bh4[4], bl4[4];
#pragma unroll
            for (int m = 0; m < 4; ++m) {
                const int r = wr64 + m * 16 + l15;
                const int byt = r * 128 + (kbyte ^ ((r & 7) << 4));
                ah[m] = *(const bf16x8*)(smb + aoffB + byt);
                al[m] = *(const bf16x8*)(smb + aoffB + 16384 + byt);
            }
#pragma unroll
            for (int n = 0; n < 4; ++n) {
                const int c = wc64 + n * 16 + l15;
                const int byt = c * 128 + (kbyte ^ ((c & 7) << 4));
                bh4[n] = *(const bf16x8*)(smb + boffB + byt);
                bl4[n] = *(const bf16x8*)(smb + boffB + 16384 + byt);
            }
#pragma unroll
            for (int m = 0; m < 4; ++m)
#pragma unroll
                for (int n = 0; n < 4; ++n)
                    acc[m][n] = __builtin_amdgcn_mfma_f32_16x16x32_bf16(
                        ah[m], bh4[n], acc[m][n], 0, 0, 0);
#pragma unroll
            for (int m = 0; m < 4; ++m)
#pragma unroll
                for (int n = 0; n < 4; ++n)
                    acc[m][n] = __builtin_amdgcn_mfma_f32_16x16x32_bf16(
                        ah[m], bl4[n], acc[m][n], 0, 0, 0);
#pragma unroll
            for (int m = 0; m < 4; ++m)
#pragma unroll
                for (int n = 0; n < 4; ++n)
                    acc[m][n] = __builtin_amdgcn_mfma_f32_16x16x32_bf16(
                        al[m], bh4[n], acc[m][n], 0, 0, 0);
        }
        __syncthreads();
    }

    const int lr = (lane >> 4) * 4, lc = lane & 15;   // C/D: col=lane&15
    if (MODE == 1) {
        float* __restrict__ outb = fout + (size_t)b * E_ * C_;
#pragma unroll
        for (int m = 0; m < 4; ++m)
#pragma unroll
            for (int n = 0; n < 4; ++n) {
                float* po = outb + (size_t)(o0 + wr64 + m * 16 + lr) * C_ +
                            wc64 + n * 16 + lc;
                const f32x4 a = acc[m][n];
#pragma unroll
                for (int j = 0; j < 4; ++j) po[(size_t)j * C_] = selu_f(a[j]);
            }
    } else if (z == 2) {
        // v: natural [b][E][C], hi only
#pragma unroll
        for (int m = 0; m < 4; ++m)
#pragma unroll
            for (int n = 0; n < 4; ++n) {
                const f32x4 a = acc[m][n];
#pragma unroll
                for (int j = 0; j < 4; ++j) {
                    const size_t idx = ((size_t)b * E_ + o0 + wr64 + m * 16 + lr + j) * C_ +
                                       wc64 + n * 16 + lc;
                    vhp[idx] = f2bf(selu_f(a[j]));
                }
            }
    } else {
        // q/k: transposed [b][c][E], split hi/lo. rows=c, cols=o.
        ushort* __restrict__ th = z ? kh : qh;
        ushort* __restrict__ tl = z ? kl : ql;
#pragma unroll
        for (int m = 0; m < 4; ++m)
#pragma unroll
            for (int n = 0; n < 4; ++n) {
                const f32x4 a = acc[m][n];
#pragma unroll
                for (int j = 0; j < 4; ++j) {
                    const int c = wr64 + m * 16 + lr + j;
                    const int o = o0 + wc64 + n * 16 + lc;
                    const size_t idx = ((size_t)b * C_ + c) * E_ + o;
                    ushort hi, lo;
                    split_bf(selu_f(a[j]), hi, lo);
                    th[idx] = hi;
                    tl[idx] = lo;
                }
            }
    }
}

// ---------------------------------------------------------------------------
// MFMA attention, one block (4 waves) per (b,h). 80 KB LDS -> 2 blocks/CU.
// QK^T: 3-term split. Softmax in registers (wave owns 32 full rows).
// P split hi/lo -> LDS (overlays q/k staging). PV: (P_hi+P_lo) x v_hi.
// All LDS tiles XOR-swizzled: byte ^= (row&7)<<4, source pre-swizzled.
// ---------------------------------------------------------------------------
__global__ __launch_bounds__(256, 2) void attn_mfma_kernel(
    const ushort* __restrict__ qTh, const ushort* __restrict__ qTl,
    const ushort* __restrict__ kTh, const ushort* __restrict__ kTl,
    const ushort* __restrict__ vh,  const float* __restrict__ combT,
    ushort* __restrict__ aTh, ushort* __restrict__ aTl)
{
    const int b = blockIdx.x, h = blockIdx.y;
    __shared__ ushort lds[40960];          // 80 KB
    ushort* sQh = lds;                     // [128][64] 16 KB
    ushort* sQl = lds + 8192;
    ushort* sKh = lds + 16384;
    ushort* sKl = lds + 24576;
    ushort* sV  = lds + 32768;             // [64][128] 16 KB
    ushort* sPh = lds;                     // overlays q/k: [128][128] 32 KB
    ushort* sPl = lds + 16384;

    const int tid = threadIdx.x, wid = tid >> 6, lane = tid & 63;

    // ---- stage q,k ([128][64], swizzled src) + v ([64][128], swizzled src)
    {
        const size_t gq = (size_t)b * C_ * E_ + h * D_;
        const int rsub = lane >> 3, chunk = lane & 7;
#pragma unroll
        for (int t = 0; t < 4; ++t) {
            const int inst = wid * 4 + t;
            const int row = inst * 8 + rsub;
            const size_t goff = (gq + (size_t)row * E_) * 2 +
                                (size_t)(chunk ^ (row & 7)) * 16;
            gll16((const char*)qTh + goff, &sQh[inst * 512]);
            gll16((const char*)qTl + goff, &sQl[inst * 512]);
            gll16((const char*)kTh + goff, &sKh[inst * 512]);
            gll16((const char*)kTl + goff, &sKl[inst * 512]);
        }
        const size_t gv = ((size_t)b * E_ + h * D_) * C_;
        const int vr = lane >> 4, vchunk = lane & 15;
#pragma unroll
        for (int t = 0; t < 4; ++t) {
            const int inst = wid * 4 + t;
            const int row = inst * 4 + vr;
            const size_t goff = (gv + (size_t)row * C_) * 2 +
                                (size_t)(vchunk ^ (row & 7)) * 16;
            gll16((const char*)vh + goff, &sV[inst * 512]);
        }
    }
    __syncthreads();

    const int i0 = wid * 32;       // this wave's 32 score rows
    const int l15 = lane & 15;

    // ---- QK^T: scores 32x128 per wave = 2 m-frags x 8 n-frags, K=64
    f32x4 acc[2][8];
#pragma unroll
    for (int m = 0; m < 2; ++m)
#pragma unroll
        for (int n = 0; n < 8; ++n) acc[m][n] = (f32x4)0.0f;

#pragma unroll
    for (int kk = 0; kk < 2; ++kk) {
        const int kbyte = kk * 64 + (lane >> 4) * 16;
        bf16x8 qhf[2], qlf[2];
#pragma unroll
        for (int m = 0; m < 2; ++m) {
            const int r = i0 + m * 16 + l15;
            const int byt = r * 128 + (kbyte ^ ((r & 7) << 4));
            qhf[m] = *(const bf16x8*)((const char*)sQh + byt);
            qlf[m] = *(const bf16x8*)((const char*)sQl + byt);
        }
#pragma unroll
        for (int n = 0; n < 8; ++n) {
            const int r = n * 16 + l15;
            const int byt = r * 128 + (kbyte ^ ((r & 7) << 4));
            const bf16x8 khf = *(const bf16x8*)((const char*)sKh + byt);
            const bf16x8 klf = *(const bf16x8*)((const char*)sKl + byt);
#pragma unroll
            for (int m = 0; m < 2; ++m) {
                acc[m][n] = __builtin_amdgcn_mfma_f32_16x16x32_bf16(
                    qhf[m], khf, acc[m][n], 0, 0, 0);
                acc[m][n] = __builtin_amdgcn_mfma_f32_16x16x32_bf16(
                    qhf[m], klf, acc[m][n], 0, 0, 0);
                acc[m][n] = __builtin_amdgcn_mfma_f32_16x16x32_bf16(
                    qlf[m], khf, acc[m][n], 0, 0, 0);
            }
        }
    }

    // ---- bias (combT float4) + masked softmax, fully in registers
#pragma unroll
    for (int m = 0; m < 2; ++m)
#pragma unroll
        for (int n = 0; n < 8; ++n) {
            const int jcol = n * 16 + l15;
            const float4 cb = *(const float4*)&combT[
                ((size_t)h * C_ + jcol) * C_ + i0 + m * 16 + (lane >> 4) * 4];
            acc[m][n][0] = fmaf(acc[m][n][0], 0.125f, cb.x);
            acc[m][n][1] = fmaf(acc[m][n][1], 0.125f, cb.y);
            acc[m][n][2] = fmaf(acc[m][n][2], 0.125f, cb.z);
            acc[m][n][3] = fmaf(acc[m][n][3], 0.125f, cb.w);
        }

#pragma unroll
    for (int m = 0; m < 2; ++m)
#pragma unroll
        for (int jj = 0; jj < 4; ++jj) {
            float mx = -INFINITY;
#pragma unroll
            for (int n = 0; n < 8; ++n) mx = fmaxf(mx, acc[m][n][jj]);
#pragma unroll
            for (int off = 1; off < 16; off <<= 1)
                mx = fmaxf(mx, __shfl_xor(mx, off));
            float sum = 0.0f;
#pragma unroll
            for (int n = 0; n < 8; ++n) {
                const float e = __expf(acc[m][n][jj] - mx);
                acc[m][n][jj] = e;
                sum += e;
            }
#pragma unroll
            for (int off = 1; off < 16; off <<= 1) sum += __shfl_xor(sum, off);
            const float inv = 1.0f / sum;
#pragma unroll
            for (int n = 0; n < 8; ++n) acc[m][n][jj] *= inv;
        }

    // ---- P -> LDS (split, swizzled). Must not race q/k reads: barrier first.
    __syncthreads();
#pragma unroll
    for (int m = 0; m < 2; ++m)
#pragma unroll
        for (int n = 0; n < 8; ++n)
#pragma unroll
            for (int jj = 0; jj < 4; ++jj) {
                const int i = i0 + m * 16 + (lane >> 4) * 4 + jj;
                const int col = n * 16 + l15;
                const int byt = i * 256 + ((col * 2) ^ ((i & 7) << 4));
                ushort hi, lo;
                split_bf(acc[m][n][jj], hi, lo);
                *(ushort*)((char*)sPh + byt) = hi;
                *(ushort*)((char*)sPl + byt) = lo;
            }
    __syncthreads();

    // ---- PV: out 32x64 per wave = 2 m-frags x 4 n-frags, K=128
    f32x4 acc2[2][4];
#pragma unroll
    for (int m = 0; m < 2; ++m)
#pragma unroll
        for (int n = 0; n < 4; ++n) acc2[m][n] = (f32x4)0.0f;

#pragma unroll
    for (int ks = 0; ks < 4; ++ks) {
        const int kbyte = ks * 64 + (lane >> 4) * 16;
        bf16x8 ph[2], pl[2];
#pragma unroll
        for (int m = 0; m < 2; ++m) {
            const int r = i0 + m * 16 + l15;
            const int byt = r * 256 + (kbyte ^ ((r & 7) << 4));
            ph[m] = *(const bf16x8*)((const char*)sPh + byt);
            pl[m] = *(const bf16x8*)((const char*)sPl + byt);
        }
#pragma unroll
        for (int n = 0; n < 4; ++n) {
            const int d = n * 16 + l15;
            const int byt = d * 256 + (kbyte ^ ((d & 7) << 4));
            const bf16x8 vb = *(const bf16x8*)((const char*)sV + byt);
#pragma unroll
            for (int m = 0; m < 2; ++m) {
                acc2[m][n] = __builtin_amdgcn_mfma_f32_16x16x32_bf16(
                    ph[m], vb, acc2[m][n], 0, 0, 0);
                acc2[m][n] = __builtin_amdgcn_mfma_f32_16x16x32_bf16(
                    pl[m], vb, acc2[m][n], 0, 0, 0);
            }
        }
    }

    // ---- epilogue: attnT[b][c][E] split hi/lo
#pragma unroll
    for (int m = 0; m < 2; ++m)
#pragma unroll
        for (int n = 0; n < 4; ++n)
#pragma unroll
            for (int jj = 0; jj < 4; ++jj) {
                const int i = i0 + m * 16 + (lane >> 4) * 4 + jj;
                const int dcol = n * 16 + l15;
                ushort hi, lo;
                split_bf(acc2[m][n][jj], hi, lo);
                const size_t idx = ((size_t)b * C_ + i) * E_ + h * D_ + dcol;
                aTh[idx] = hi;
                aTl[idx] = lo;
            }
}

// ---------------------------------------------------------------------------
extern "C" void kernel_launch(void* const* d_in, const int* in_sizes, int n_in,
                              void* d_out, int out_size, void* d_ws, size_t ws_size,
                              hipStream_t stream) {
    const float* x        = (const float*)d_in[0];
    const float* wq       = (const float*)d_in[1];
    const float* wk       = (const float*)d_in[2];
    const float* wv       = (const float*)d_in[3];
    const float* wo       = (const float*)d_in[4];
    const float* dir_vec  = (const float*)d_in[5];
    const float* attn_b   = (const float*)d_in[6];
    const float* disp     = (const float*)d_in[7];
    const unsigned char* knn = (const unsigned char*)d_in[8];
    float* out = (float*)d_out;

    // workspace: 7 bf16 planes of BEC + weights + bias (~122 MB)
    char* ws = (char*)d_ws;
    size_t off = 0;
    ushort* qTh = (ushort*)(ws + off); off += BEC_ * 2;
    ushort* qTl = (ushort*)(ws + off); off += BEC_ * 2;
    ushort* kTh = (ushort*)(ws + off); off += BEC_ * 2;
    ushort* kTl = (ushort*)(ws + off); off += BEC_ * 2;
    ushort* vbuf = (ushort*)(ws + off); off += BEC_ * 2;
    ushort* xTh = (ushort*)(ws + off); off += BEC_ * 2;   // reused as attnT hi
    ushort* xTl = (ushort*)(ws + off); off += BEC_ * 2;   // reused as attnT lo
    ushort* wh  = (ushort*)(ws + off); off += (size_t)4 * E_ * E_ * 2;
    ushort* wl  = (ushort*)(ws + off); off += (size_t)4 * E_ * E_ * 2;
    float* combT = (float*)(ws + off); off += (size_t)H_ * C_ * C_ * sizeof(float);
    int* flag = (int*)(ws + off);

    detect_mask_kernel<<<1, 256, 0, stream>>>(knn, flag);
    bias_prep_kernel<<<dim3(C_, H_), 128, 0, stream>>>(dir_vec, attn_b, disp, knn,
                                                       flag, combT);
    wsplit_kernel<<<dim3(128, 4), 256, 0, stream>>>(wq, wk, wv, wo, wh, wl);
    xsplit_kernel<<<dim3(8, B_), 256, 0, stream>>>(x, xTh, xTl);

    const size_t WSZ = (size_t)E_ * E_;
    // q (trans), k (trans), v (natural hi) in one launch
    gemm_kernel<0><<<dim3(4, B_, 3), 256, 0, stream>>>(
        wh, wh + WSZ, wh + 2 * WSZ, wl, wl + WSZ, wl + 2 * WSZ,
        xTh, xTl, qTh, qTl, kTh, kTl, vbuf, nullptr);
    // MFMA attention -> attnT over xT buffers
    attn_mfma_kernel<<<dim3(B_, H_), 256, 0, stream>>>(
        qTh, qTl, kTh, kTl, vbuf, combT, xTh, xTl);
    // output projection -> d_out (fp32 + selu)
    gemm_kernel<1><<<dim3(4, B_, 1), 256, 0, stream>>>(
        wh + 3 * WSZ, wh + 3 * WSZ, wh + 3 * WSZ,
        wl + 3 * WSZ, wl + 3 * WSZ, wl + 3 * WSZ,
        xTh, xTl, nullptr, nullptr, nullptr, nullptr, nullptr, out);
}

// Round 7
// 214.090 us; speedup vs baseline: 1.0247x; 1.0247x over previous
//
#include <hip/hip_runtime.h>
#include <math.h>

#define B_ 128
#define E_ 512
#define C_ 128
#define H_ 8
#define D_ 64
#define BEC_ ((size_t)B_ * E_ * C_)

typedef __attribute__((ext_vector_type(8))) __bf16 bf16x8;
typedef __attribute__((ext_vector_type(4))) float f32x4;

__device__ __forceinline__ ushort f2bf(float f) {
    unsigned u = __float_as_uint(f);
    unsigned r = u + 0x7fffu + ((u >> 16) & 1u);
    return (ushort)(r >> 16);
}
__device__ __forceinline__ float bf2f(ushort h) {
    return __uint_as_float(((unsigned)h) << 16);
}
__device__ __forceinline__ void split_bf(float f, ushort& hi, ushort& lo) {
    hi = f2bf(f);
    lo = f2bf(f - bf2f(hi));
}
__device__ __forceinline__ float selu_f(float x) {
    const float alpha = 1.6732632423543772f;
    const float scale = 1.0507009873554805f;
    return x > 0.0f ? scale * x : scale * alpha * expm1f(x);
}
// async global->LDS, 16B/lane; LDS dest wave-uniform base + lane*16
__device__ __forceinline__ void gll16(const void* g, void* l) {
    __builtin_amdgcn_global_load_lds(
        (const __attribute__((address_space(1))) void*)g,
        (__attribute__((address_space(3))) void*)l, 16, 0, 0);
}

// ---------------------------------------------------------------------------
// knn_mask dtype sniff (bool bytes -> 2688 nonzero in 16KB, int32 -> 672)
// ---------------------------------------------------------------------------
__global__ void detect_mask_kernel(const unsigned char* __restrict__ m,
                                   int* __restrict__ flag) {
    __shared__ int cnt;
    if (threadIdx.x == 0) cnt = 0;
    __syncthreads();
    int local = 0;
    for (int i = threadIdx.x; i < C_ * C_; i += blockDim.x) local += (m[i] != 0);
    atomicAdd(&cnt, local);
    __syncthreads();
    if (threadIdx.x == 0) *flag = (cnt > 1600) ? 1 : 0;
}

// ---------------------------------------------------------------------------
// combT[h][j][i] = mask(i,j) ? attn_bias[i][j] + centered dir bias(i,j) : -inf
// ---------------------------------------------------------------------------
__global__ __launch_bounds__(128) void bias_prep_kernel(
    const float* __restrict__ dir_vec, const float* __restrict__ attn_bias,
    const float* __restrict__ disp, const unsigned char* __restrict__ maskb,
    const int* __restrict__ flag, float* __restrict__ combT)
{
    const int i = blockIdx.x, h = blockIdx.y, j = threadIdx.x;
    __shared__ float red[128];

    float dv = dir_vec[h * C_ + j];
    red[j] = dv * dv;
    __syncthreads();
    for (int s = 64; s > 0; s >>= 1) {
        if (j < s) red[j] += red[j + s];
        __syncthreads();
    }
    const float nrm = fmaxf(sqrtf(red[0]), 1e-12f);
    __syncthreads();

    const float dvn_j = dir_vec[h * C_ + j] / nrm;
    const float dvn_i = dir_vec[h * C_ + i] / nrm;
    const float third = 1.0f / 3.0f;
    const float dm_ij = (disp[(i * C_ + j) * 3 + 0] + disp[(i * C_ + j) * 3 + 1] +
                         disp[(i * C_ + j) * 3 + 2]) * third;
    const float dm_ji = (disp[(j * C_ + i) * 3 + 0] + disp[(j * C_ + i) * 3 + 1] +
                         disp[(j * C_ + i) * 3 + 2]) * third;
    const float db = 0.5f * (dm_ij * dvn_j - dm_ji * dvn_i);

    red[j] = db;
    __syncthreads();
    for (int s = 64; s > 0; s >>= 1) {
        if (j < s) red[j] += red[j + s];
        __syncthreads();
    }
    const float rowmean = red[0] * (1.0f / 128.0f);

    const bool mk = (*flag) ? (maskb[i * C_ + j] != 0)
                            : (((const int*)maskb)[i * C_ + j] != 0);
    combT[((size_t)h * C_ + j) * C_ + i] =
        mk ? (attn_bias[i * C_ + j] + db - rowmean) : -INFINITY;
}

// ---------------------------------------------------------------------------
// Split the 4 weight matrices [E][E] fp32 -> hi/lo bf16, stacked [4E][E].
// ---------------------------------------------------------------------------
__global__ __launch_bounds__(256) void wsplit_kernel(
    const float* __restrict__ w0, const float* __restrict__ w1,
    const float* __restrict__ w2, const float* __restrict__ w3,
    ushort* __restrict__ wh, ushort* __restrict__ wl)
{
    const int s = blockIdx.y;
    const float* __restrict__ w = (s == 0) ? w0 : (s == 1) ? w1 : (s == 2) ? w2 : w3;
    const size_t base = (size_t)s * E_ * E_;
    const size_t i0 = ((size_t)blockIdx.x * 256 + threadIdx.x) * 8;
    const float4 f0 = *(const float4*)&w[i0];
    const float4 f1 = *(const float4*)&w[i0 + 4];
    const float ff[8] = {f0.x, f0.y, f0.z, f0.w, f1.x, f1.y, f1.z, f1.w};
    union { ushort u[8]; uint4 v; } hu, lu;
#pragma unroll
    for (int j = 0; j < 8; ++j) split_bf(ff[j], hu.u[j], lu.u[j]);
    *(uint4*)&wh[base + i0] = hu.v;
    *(uint4*)&wl[base + i0] = lu.v;
}

// ---------------------------------------------------------------------------
// x [B][E][C] fp32 -> xT hi/lo bf16 [B*C][E]  (transpose + split)
// ---------------------------------------------------------------------------
__global__ __launch_bounds__(256) void xsplit_kernel(
    const float* __restrict__ x, ushort* __restrict__ xh, ushort* __restrict__ xl)
{
    const int b = blockIdx.y, e0 = blockIdx.x * 64;
    __shared__ float ts[64][132];
    const int tid = threadIdx.x;
    const float* __restrict__ xb = x + ((size_t)b * E_ + e0) * C_;
#pragma unroll
    for (int r = 0; r < 8; ++r) {
        const int idx = tid + r * 256;
        const int e = idx >> 5, c4 = idx & 31;
        *(float4*)&ts[e][c4 * 4] = *(const float4*)&xb[(size_t)e * C_ + c4 * 4];
    }
    __syncthreads();
    const int lc = tid >> 3;
    const int l8 = (tid & 7) * 8;
#pragma unroll
    for (int p = 0; p < 4; ++p) {
        const int c = p * 32 + lc;
        union { ushort u[8]; uint4 v; } hu, lu;
#pragma unroll
        for (int j = 0; j < 8; ++j) split_bf(ts[l8 + j][c], hu.u[j], lu.u[j]);
        const size_t rb = ((size_t)b * C_ + c) * E_ + e0 + l8;
        *(uint4*)&xh[rb] = hu.v;
        *(uint4*)&xl[rb] = lu.v;
    }
}

// ---------------------------------------------------------------------------
// Pipelined split-bf16 MFMA GEMM (T3/T4/T5 port).
// Tile 128(o) x 256(c), BK=32, 8 waves (2x4, each 64x64), 3-term split.
// LDS: 3 buffers x 48KB {Wh 8K | Wl 8K | Xh 16K | Xl 16K}, rows 64B (bank-
// uniform, no swizzle). Per K-tile: 2 phases; stage(t+3) issued after the
// reads-done barrier into the just-freed buffer; counted vmcnt(12) (never 0
// in-loop); raw s_barrier + setprio around MFMA clusters.
// MODE 0: merged qkv, M=1536 (z = bx>>2): q/k transposed split stores,
//         v natural hi-only.  MODE 1: out-proj fp32+selu.
// ---------------------------------------------------------------------------
template<int MODE>
__global__ __launch_bounds__(512, 1) void gemm8_kernel(
    const ushort* __restrict__ Wh, const ushort* __restrict__ Wl,
    const ushort* __restrict__ Bh, const ushort* __restrict__ Bl,
    ushort* __restrict__ qh, ushort* __restrict__ ql,
    ushort* __restrict__ kh, ushort* __restrict__ kl,
    ushort* __restrict__ vhp, float* __restrict__ fout)
{
    __shared__ ushort lds[3 * 24576];   // 144 KB

    // T1: bijective XCD remap (nwg % 8 == 0 in both modes)
    const int NB = (MODE == 0) ? 12 : 4;
    const int nwg = NB * 64;
    const int w = blockIdx.x + NB * blockIdx.y;
    const int l = (w & 7) * (nwg >> 3) + (w >> 3);
    const int bx = l % NB, bgrp = l / NB;

    const int tid = threadIdx.x, wid = tid >> 6, lane = tid & 63;
    const int o0 = bx * 128;
    const int wr = wid >> 2, wc = wid & 3, l15 = lane & 15;
    const int kq = (lane >> 4) * 16;    // byte chunk within 64B row

    // ---- precompute this wave's 6 stage instructions (t-independent parts)
    const char* sp[6];
    size_t so[6];
    int lo_[6];
#pragma unroll
    for (int q = 0; q < 6; ++q) {
        const int g = wid * 6 + q;
        int stream, inst;
        if (g < 8)       { stream = 0; inst = g; }
        else if (g < 16) { stream = 1; inst = g - 8; }
        else if (g < 32) { stream = 2; inst = g - 16; }
        else             { stream = 3; inst = g - 32; }
        const int rowbase = (stream < 2) ? (o0 + inst * 16)
                                         : (bgrp * 256 + inst * 16);
        sp[q] = (stream == 0) ? (const char*)Wh : (stream == 1) ? (const char*)Wl
              : (stream == 2) ? (const char*)Bh : (const char*)Bl;
        so[q] = ((size_t)(rowbase + (lane >> 2)) * E_) * 2 + (size_t)(lane & 3) * 16;
        lo_[q] = ((stream == 0) ? 0 : (stream == 1) ? 4096 :
                  (stream == 2) ? 8192 : 16384) + inst * 512;   // ushort units
    }

    // frag byte offsets within a buffer (A rows [0,128), B rows [0,256))
    int aoff[4], boff[4];
#pragma unroll
    for (int m = 0; m < 4; ++m) aoff[m] = (wr * 64 + m * 16 + l15) * 64 + kq;
#pragma unroll
    for (int n = 0; n < 4; ++n) boff[n] = (wc * 64 + n * 16 + l15) * 64 + kq;

    f32x4 acc[4][4];
#pragma unroll
    for (int m = 0; m < 4; ++m)
#pragma unroll
        for (int n = 0; n < 4; ++n) acc[m][n] = (f32x4)0.0f;

    // ---- prologue: stage K-tiles 0,1,2
#pragma unroll
    for (int p = 0; p < 3; ++p) {
#pragma unroll
        for (int q = 0; q < 6; ++q)
            gll16(sp[q] + so[q] + (size_t)p * 64, &lds[p * 24576 + lo_[q]]);
    }

    int cur = 0;
    for (int t = 0; t < 16; ++t) {
        const char* bb = (const char*)lds + cur * 49152;

        asm volatile("s_waitcnt vmcnt(12)" ::: "memory");   // stage(t) landed
        __builtin_amdgcn_s_barrier();
        __builtin_amdgcn_sched_barrier(0);

        // -------- phase A: read A m0..1 + all B, MFMA m0..1
        bf16x8 ah[4], al[4], bh4[4], bl4[4];
#pragma unroll
        for (int m = 0; m < 2; ++m) {
            ah[m] = *(const bf16x8*)(bb + aoff[m]);
            al[m] = *(const bf16x8*)(bb + 8192 + aoff[m]);
        }
#pragma unroll
        for (int n = 0; n < 4; ++n) {
            bh4[n] = *(const bf16x8*)(bb + 16384 + boff[n]);
            bl4[n] = *(const bf16x8*)(bb + 32768 + boff[n]);
        }
        __builtin_amdgcn_s_setprio(1);
#pragma unroll
        for (int m = 0; m < 2; ++m)
#pragma unroll
            for (int n = 0; n < 4; ++n) {
                acc[m][n] = __builtin_amdgcn_mfma_f32_16x16x32_bf16(
                    ah[m], bh4[n], acc[m][n], 0, 0, 0);
                acc[m][n] = __builtin_amdgcn_mfma_f32_16x16x32_bf16(
                    ah[m], bl4[n], acc[m][n], 0, 0, 0);
                acc[m][n] = __builtin_amdgcn_mfma_f32_16x16x32_bf16(
                    al[m], bh4[n], acc[m][n], 0, 0, 0);
            }
        __builtin_amdgcn_s_setprio(0);

        // -------- phase B: read A m2..3, drain LDS reads, free the buffer,
        //          issue stage(t+3) into it, then MFMA m2..3
#pragma unroll
        for (int m = 2; m < 4; ++m) {
            ah[m] = *(const bf16x8*)(bb + aoff[m]);
            al[m] = *(const bf16x8*)(bb + 8192 + aoff[m]);
        }
        asm volatile("s_waitcnt lgkmcnt(0)" ::: "memory");
        __builtin_amdgcn_sched_barrier(0);
        __builtin_amdgcn_s_barrier();       // all waves done reading buf[cur]

        {
            const int kt = (t + 3 > 15) ? 15 : t + 3;   // dummy tail keeps
#pragma unroll                                           // vmcnt(12) uniform
            for (int q = 0; q < 6; ++q)
                gll16(sp[q] + so[q] + (size_t)kt * 64, &lds[cur * 24576 + lo_[q]]);
        }

        __builtin_amdgcn_s_setprio(1);
#pragma unroll
        for (int m = 2; m < 4; ++m)
#pragma unroll
            for (int n = 0; n < 4; ++n) {
                acc[m][n] = __builtin_amdgcn_mfma_f32_16x16x32_bf16(
                    ah[m], bh4[n], acc[m][n], 0, 0, 0);
                acc[m][n] = __builtin_amdgcn_mfma_f32_16x16x32_bf16(
                    ah[m], bl4[n], acc[m][n], 0, 0, 0);
                acc[m][n] = __builtin_amdgcn_mfma_f32_16x16x32_bf16(
                    al[m], bh4[n], acc[m][n], 0, 0, 0);
            }
        __builtin_amdgcn_s_setprio(0);

        cur = (cur == 2) ? 0 : cur + 1;
    }
    asm volatile("s_waitcnt vmcnt(0)" ::: "memory");   // drain dummy stages

    // ---- epilogue. C/D: col(lane&15) = c-dim, row((lane>>4)*4+j) = o-dim.
    const int lr4 = (lane >> 4) * 4;
    if (MODE == 1) {
        const int ob = bx * 128 + wr * 64;
#pragma unroll
        for (int m = 0; m < 4; ++m)
#pragma unroll
            for (int n = 0; n < 4; ++n) {
                const int R = bgrp * 256 + wc * 64 + n * 16 + l15;  // b*C+c
                float* po = fout + ((size_t)(R >> 7) * E_ + ob + m * 16 + lr4) * C_ +
                            (R & 127);
                const f32x4 a = acc[m][n];
#pragma unroll
                for (int j = 0; j < 4; ++j) po[(size_t)j * C_] = selu_f(a[j]);
            }
    } else {
        const int z = bx >> 2;
        const int wo0 = (bx & 3) * 128 + wr * 64;
        if (z == 2) {
#pragma unroll
            for (int m = 0; m < 4; ++m)
#pragma unroll
                for (int n = 0; n < 4; ++n) {
                    const int R = bgrp * 256 + wc * 64 + n * 16 + l15;
                    const f32x4 a = acc[m][n];
#pragma unroll
                    for (int j = 0; j < 4; ++j)
                        vhp[((size_t)(R >> 7) * E_ + wo0 + m * 16 + lr4 + j) * C_ +
                            (R & 127)] = f2bf(selu_f(a[j]));
                }
        } else {
            ushort* __restrict__ th = z ? kh : qh;
            ushort* __restrict__ tl = z ? kl : ql;
#pragma unroll
            for (int m = 0; m < 4; ++m)
#pragma unroll
                for (int n = 0; n < 4; ++n) {
                    const int R = bgrp * 256 + wc * 64 + n * 16 + l15;
                    const int ol = wo0 + m * 16 + lr4;
                    union { ushort u[4]; uint2 v; } hu, lu;
                    const f32x4 a = acc[m][n];
#pragma unroll
                    for (int j = 0; j < 4; ++j) split_bf(selu_f(a[j]), hu.u[j], lu.u[j]);
                    *(uint2*)&th[(size_t)R * E_ + ol] = hu.v;
                    *(uint2*)&tl[(size_t)R * E_ + ol] = lu.v;
                }
        }
    }
}

// ---------------------------------------------------------------------------
// MFMA attention, one block (4 waves) per (b,h). 80 KB LDS -> 2 blocks/CU.
// (unchanged from round 4/6 — verified passing)
// ---------------------------------------------------------------------------
__global__ __launch_bounds__(256, 2) void attn_mfma_kernel(
    const ushort* __restrict__ qTh, const ushort* __restrict__ qTl,
    const ushort* __restrict__ kTh, const ushort* __restrict__ kTl,
    const ushort* __restrict__ vh,  const float* __restrict__ combT,
    ushort* __restrict__ aTh, ushort* __restrict__ aTl)
{
    const int b = blockIdx.x, h = blockIdx.y;
    __shared__ ushort lds[40960];
    ushort* sQh = lds;
    ushort* sQl = lds + 8192;
    ushort* sKh = lds + 16384;
    ushort* sKl = lds + 24576;
    ushort* sV  = lds + 32768;
    ushort* sPh = lds;
    ushort* sPl = lds + 16384;

    const int tid = threadIdx.x, wid = tid >> 6, lane = tid & 63;

    {
        const size_t gq = (size_t)b * C_ * E_ + h * D_;
        const int rsub = lane >> 3, chunk = lane & 7;
#pragma unroll
        for (int t = 0; t < 4; ++t) {
            const int inst = wid * 4 + t;
            const int row = inst * 8 + rsub;
            const size_t goff = (gq + (size_t)row * E_) * 2 +
                                (size_t)(chunk ^ (row & 7)) * 16;
            gll16((const char*)qTh + goff, &sQh[inst * 512]);
            gll16((const char*)qTl + goff, &sQl[inst * 512]);
            gll16((const char*)kTh + goff, &sKh[inst * 512]);
            gll16((const char*)kTl + goff, &sKl[inst * 512]);
        }
        const size_t gv = ((size_t)b * E_ + h * D_) * C_;
        const int vr = lane >> 4, vchunk = lane & 15;
#pragma unroll
        for (int t = 0; t < 4; ++t) {
            const int inst = wid * 4 + t;
            const int row = inst * 4 + vr;
            const size_t goff = (gv + (size_t)row * C_) * 2 +
                                (size_t)(vchunk ^ (row & 7)) * 16;
            gll16((const char*)vh + goff, &sV[inst * 512]);
        }
    }
    __syncthreads();

    const int i0 = wid * 32;
    const int l15 = lane & 15;

    f32x4 acc[2][8];
#pragma unroll
    for (int m = 0; m < 2; ++m)
#pragma unroll
        for (int n = 0; n < 8; ++n) acc[m][n] = (f32x4)0.0f;

#pragma unroll
    for (int kk = 0; kk < 2; ++kk) {
        const int kbyte = kk * 64 + (lane >> 4) * 16;
        bf16x8 qhf[2], qlf[2];
#pragma unroll
        for (int m = 0; m < 2; ++m) {
            const int r = i0 + m * 16 + l15;
            const int byt = r * 128 + (kbyte ^ ((r & 7) << 4));
            qhf[m] = *(const bf16x8*)((const char*)sQh + byt);
            qlf[m] = *(const bf16x8*)((const char*)sQl + byt);
        }
#pragma unroll
        for (int n = 0; n < 8; ++n) {
            const int r = n * 16 + l15;
            const int byt = r * 128 + (kbyte ^ ((r & 7) << 4));
            const bf16x8 khf = *(const bf16x8*)((const char*)sKh + byt);
            const bf16x8 klf = *(const bf16x8*)((const char*)sKl + byt);
#pragma unroll
            for (int m = 0; m < 2; ++m) {
                acc[m][n] = __builtin_amdgcn_mfma_f32_16x16x32_bf16(
                    qhf[m], khf, acc[m][n], 0, 0, 0);
                acc[m][n] = __builtin_amdgcn_mfma_f32_16x16x32_bf16(
                    qhf[m], klf, acc[m][n], 0, 0, 0);
                acc[m][n] = __builtin_amdgcn_mfma_f32_16x16x32_bf16(
                    qlf[m], khf, acc[m][n], 0, 0, 0);
            }
        }
    }

#pragma unroll
    for (int m = 0; m < 2; ++m)
#pragma unroll
        for (int n = 0; n < 8; ++n) {
            const int jcol = n * 16 + l15;
            const float4 cb = *(const float4*)&combT[
                ((size_t)h * C_ + jcol) * C_ + i0 + m * 16 + (lane >> 4) * 4];
            acc[m][n][0] = fmaf(acc[m][n][0], 0.125f, cb.x);
            acc[m][n][1] = fmaf(acc[m][n][1], 0.125f, cb.y);
            acc[m][n][2] = fmaf(acc[m][n][2], 0.125f, cb.z);
            acc[m][n][3] = fmaf(acc[m][n][3], 0.125f, cb.w);
        }

#pragma unroll
    for (int m = 0; m < 2; ++m)
#pragma unroll
        for (int jj = 0; jj < 4; ++jj) {
            float mx = -INFINITY;
#pragma unroll
            for (int n = 0; n < 8; ++n) mx = fmaxf(mx, acc[m][n][jj]);
#pragma unroll
            for (int off = 1; off < 16; off <<= 1)
                mx = fmaxf(mx, __shfl_xor(mx, off));
            float sum = 0.0f;
#pragma unroll
            for (int n = 0; n < 8; ++n) {
                const float e = __expf(acc[m][n][jj] - mx);
                acc[m][n][jj] = e;
                sum += e;
            }
#pragma unroll
            for (int off = 1; off < 16; off <<= 1) sum += __shfl_xor(sum, off);
            const float inv = 1.0f / sum;
#pragma unroll
            for (int n = 0; n < 8; ++n) acc[m][n][jj] *= inv;
        }

    __syncthreads();
#pragma unroll
    for (int m = 0; m < 2; ++m)
#pragma unroll
        for (int n = 0; n < 8; ++n)
#pragma unroll
            for (int jj = 0; jj < 4; ++jj) {
                const int i = i0 + m * 16 + (lane >> 4) * 4 + jj;
                const int col = n * 16 + l15;
                const int byt = i * 256 + ((col * 2) ^ ((i & 7) << 4));
                ushort hi, lo;
                split_bf(acc[m][n][jj], hi, lo);
                *(ushort*)((char*)sPh + byt) = hi;
                *(ushort*)((char*)sPl + byt) = lo;
            }
    __syncthreads();

    f32x4 acc2[2][4];
#pragma unroll
    for (int m = 0; m < 2; ++m)
#pragma unroll
        for (int n = 0; n < 4; ++n) acc2[m][n] = (f32x4)0.0f;

#pragma unroll
    for (int ks = 0; ks < 4; ++ks) {
        const int kbyte = ks * 64 + (lane >> 4) * 16;
        bf16x8 ph[2], pl[2];
#pragma unroll
        for (int m = 0; m < 2; ++m) {
            const int r = i0 + m * 16 + l15;
            const int byt = r * 256 + (kbyte ^ ((r & 7) << 4));
            ph[m] = *(const bf16x8*)((const char*)sPh + byt);
            pl[m] = *(const bf16x8*)((const char*)sPl + byt);
        }
#pragma unroll
        for (int n = 0; n < 4; ++n) {
            const int d = n * 16 + l15;
            const int byt = d * 256 + (kbyte ^ ((d & 7) << 4));
            const bf16x8 vb = *(const bf16x8*)((const char*)sV + byt);
#pragma unroll
            for (int m = 0; m < 2; ++m) {
                acc2[m][n] = __builtin_amdgcn_mfma_f32_16x16x32_bf16(
                    ph[m], vb, acc2[m][n], 0, 0, 0);
                acc2[m][n] = __builtin_amdgcn_mfma_f32_16x16x32_bf16(
                    pl[m], vb, acc2[m][n], 0, 0, 0);
            }
        }
    }

#pragma unroll
    for (int m = 0; m < 2; ++m)
#pragma unroll
        for (int n = 0; n < 4; ++n)
#pragma unroll
            for (int jj = 0; jj < 4; ++jj) {
                const int i = i0 + m * 16 + (lane >> 4) * 4 + jj;
                const int dcol = n * 16 + l15;
                ushort hi, lo;
                split_bf(acc2[m][n][jj], hi, lo);
                const size_t idx = ((size_t)b * C_ + i) * E_ + h * D_ + dcol;
                aTh[idx] = hi;
                aTl[idx] = lo;
            }
}

// ---------------------------------------------------------------------------
extern "C" void kernel_launch(void* const* d_in, const int* in_sizes, int n_in,
                              void* d_out, int out_size, void* d_ws, size_t ws_size,
                              hipStream_t stream) {
    const float* x        = (const float*)d_in[0];
    const float* wq       = (const float*)d_in[1];
    const float* wk       = (const float*)d_in[2];
    const float* wv       = (const float*)d_in[3];
    const float* wo       = (const float*)d_in[4];
    const float* dir_vec  = (const float*)d_in[5];
    const float* attn_b   = (const float*)d_in[6];
    const float* disp     = (const float*)d_in[7];
    const unsigned char* knn = (const unsigned char*)d_in[8];
    float* out = (float*)d_out;

    char* ws = (char*)d_ws;
    size_t off = 0;
    ushort* qTh = (ushort*)(ws + off); off += BEC_ * 2;
    ushort* qTl = (ushort*)(ws + off); off += BEC_ * 2;
    ushort* kTh = (ushort*)(ws + off); off += BEC_ * 2;
    ushort* kTl = (ushort*)(ws + off); off += BEC_ * 2;
    ushort* vbuf = (ushort*)(ws + off); off += BEC_ * 2;
    ushort* xTh = (ushort*)(ws + off); off += BEC_ * 2;   // reused as attnT hi
    ushort* xTl = (ushort*)(ws + off); off += BEC_ * 2;   // reused as attnT lo
    ushort* wh  = (ushort*)(ws + off); off += (size_t)4 * E_ * E_ * 2;
    ushort* wl  = (ushort*)(ws + off); off += (size_t)4 * E_ * E_ * 2;
    float* combT = (float*)(ws + off); off += (size_t)H_ * C_ * C_ * sizeof(float);
    int* flag = (int*)(ws + off);

    detect_mask_kernel<<<1, 256, 0, stream>>>(knn, flag);
    bias_prep_kernel<<<dim3(C_, H_), 128, 0, stream>>>(dir_vec, attn_b, disp, knn,
                                                       flag, combT);
    wsplit_kernel<<<dim3(128, 4), 256, 0, stream>>>(wq, wk, wv, wo, wh, wl);
    xsplit_kernel<<<dim3(8, B_), 256, 0, stream>>>(x, xTh, xTl);

    const size_t WSZ = (size_t)E_ * E_;
    // merged qkv (M=1536) pipelined GEMM
    gemm8_kernel<0><<<dim3(12, 64), 512, 0, stream>>>(
        wh, wl, xTh, xTl, qTh, qTl, kTh, kTl, vbuf, nullptr);
    // MFMA attention -> attnT over xT buffers
    attn_mfma_kernel<<<dim3(B_, H_), 256, 0, stream>>>(
        qTh, qTl, kTh, kTl, vbuf, combT, xTh, xTl);
    // output projection -> d_out
    gemm8_kernel<1><<<dim3(4, 64), 512, 0, stream>>>(
        wh + 3 * WSZ, wl + 3 * WSZ, xTh, xTl,
        nullptr, nullptr, nullptr, nullptr, nullptr, out);
}

// Round 8
// 211.634 us; speedup vs baseline: 1.0365x; 1.0116x over previous
//
#include <hip/hip_runtime.h>
#include <math.h>

#define B_ 128
#define E_ 512
#define C_ 128
#define H_ 8
#define D_ 64
#define BEC_ ((size_t)B_ * E_ * C_)

typedef __attribute__((ext_vector_type(8))) __bf16 bf16x8;
typedef __attribute__((ext_vector_type(4))) float f32x4;

__device__ __forceinline__ ushort f2bf(float f) {
    unsigned u = __float_as_uint(f);
    unsigned r = u + 0x7fffu + ((u >> 16) & 1u);
    return (ushort)(r >> 16);
}
__device__ __forceinline__ float bf2f(ushort h) {
    return __uint_as_float(((unsigned)h) << 16);
}
__device__ __forceinline__ void split_bf(float f, ushort& hi, ushort& lo) {
    hi = f2bf(f);
    lo = f2bf(f - bf2f(hi));
}
__device__ __forceinline__ float selu_f(float x) {
    const float alpha = 1.6732632423543772f;
    const float scale = 1.0507009873554805f;
    return x > 0.0f ? scale * x : scale * alpha * expm1f(x);
}
// async global->LDS, 16B/lane; LDS dest wave-uniform base + lane*16
__device__ __forceinline__ void gll16(const void* g, void* l) {
    __builtin_amdgcn_global_load_lds(
        (const __attribute__((address_space(1))) void*)g,
        (__attribute__((address_space(3))) void*)l, 16, 0, 0);
}

// ---------------------------------------------------------------------------
// knn_mask dtype sniff (bool bytes -> 2688 nonzero in 16KB, int32 -> 672)
// ---------------------------------------------------------------------------
__global__ void detect_mask_kernel(const unsigned char* __restrict__ m,
                                   int* __restrict__ flag) {
    __shared__ int cnt;
    if (threadIdx.x == 0) cnt = 0;
    __syncthreads();
    int local = 0;
    for (int i = threadIdx.x; i < C_ * C_; i += blockDim.x) local += (m[i] != 0);
    atomicAdd(&cnt, local);
    __syncthreads();
    if (threadIdx.x == 0) *flag = (cnt > 1600) ? 1 : 0;
}

// ---------------------------------------------------------------------------
// combT[h][j][i] = mask(i,j) ? attn_bias[i][j] + centered dir bias(i,j) : -inf
// ---------------------------------------------------------------------------
__global__ __launch_bounds__(128) void bias_prep_kernel(
    const float* __restrict__ dir_vec, const float* __restrict__ attn_bias,
    const float* __restrict__ disp, const unsigned char* __restrict__ maskb,
    const int* __restrict__ flag, float* __restrict__ combT)
{
    const int i = blockIdx.x, h = blockIdx.y, j = threadIdx.x;
    __shared__ float red[128];

    float dv = dir_vec[h * C_ + j];
    red[j] = dv * dv;
    __syncthreads();
    for (int s = 64; s > 0; s >>= 1) {
        if (j < s) red[j] += red[j + s];
        __syncthreads();
    }
    const float nrm = fmaxf(sqrtf(red[0]), 1e-12f);
    __syncthreads();

    const float dvn_j = dir_vec[h * C_ + j] / nrm;
    const float dvn_i = dir_vec[h * C_ + i] / nrm;
    const float third = 1.0f / 3.0f;
    const float dm_ij = (disp[(i * C_ + j) * 3 + 0] + disp[(i * C_ + j) * 3 + 1] +
                         disp[(i * C_ + j) * 3 + 2]) * third;
    const float dm_ji = (disp[(j * C_ + i) * 3 + 0] + disp[(j * C_ + i) * 3 + 1] +
                         disp[(j * C_ + i) * 3 + 2]) * third;
    const float db = 0.5f * (dm_ij * dvn_j - dm_ji * dvn_i);

    red[j] = db;
    __syncthreads();
    for (int s = 64; s > 0; s >>= 1) {
        if (j < s) red[j] += red[j + s];
        __syncthreads();
    }
    const float rowmean = red[0] * (1.0f / 128.0f);

    const bool mk = (*flag) ? (maskb[i * C_ + j] != 0)
                            : (((const int*)maskb)[i * C_ + j] != 0);
    combT[((size_t)h * C_ + j) * C_ + i] =
        mk ? (attn_bias[i * C_ + j] + db - rowmean) : -INFINITY;
}

// ---------------------------------------------------------------------------
// Split the 4 weight matrices [E][E] fp32 -> hi/lo bf16, stacked [4E][E].
// ---------------------------------------------------------------------------
__global__ __launch_bounds__(256) void wsplit_kernel(
    const float* __restrict__ w0, const float* __restrict__ w1,
    const float* __restrict__ w2, const float* __restrict__ w3,
    ushort* __restrict__ wh, ushort* __restrict__ wl)
{
    const int s = blockIdx.y;
    const float* __restrict__ w = (s == 0) ? w0 : (s == 1) ? w1 : (s == 2) ? w2 : w3;
    const size_t base = (size_t)s * E_ * E_;
    const size_t i0 = ((size_t)blockIdx.x * 256 + threadIdx.x) * 8;
    const float4 f0 = *(const float4*)&w[i0];
    const float4 f1 = *(const float4*)&w[i0 + 4];
    const float ff[8] = {f0.x, f0.y, f0.z, f0.w, f1.x, f1.y, f1.z, f1.w};
    union { ushort u[8]; uint4 v; } hu, lu;
#pragma unroll
    for (int j = 0; j < 8; ++j) split_bf(ff[j], hu.u[j], lu.u[j]);
    *(uint4*)&wh[base + i0] = hu.v;
    *(uint4*)&wl[base + i0] = lu.v;
}

// ---------------------------------------------------------------------------
// x [B][E][C] fp32 -> xT hi/lo bf16 [B*C][E]  (transpose + split)
// ---------------------------------------------------------------------------
__global__ __launch_bounds__(256) void xsplit_kernel(
    const float* __restrict__ x, ushort* __restrict__ xh, ushort* __restrict__ xl)
{
    const int b = blockIdx.y, e0 = blockIdx.x * 64;
    __shared__ float ts[64][132];
    const int tid = threadIdx.x;
    const float* __restrict__ xb = x + ((size_t)b * E_ + e0) * C_;
#pragma unroll
    for (int r = 0; r < 8; ++r) {
        const int idx = tid + r * 256;
        const int e = idx >> 5, c4 = idx & 31;
        *(float4*)&ts[e][c4 * 4] = *(const float4*)&xb[(size_t)e * C_ + c4 * 4];
    }
    __syncthreads();
    const int lc = tid >> 3;
    const int l8 = (tid & 7) * 8;
#pragma unroll
    for (int p = 0; p < 4; ++p) {
        const int c = p * 32 + lc;
        union { ushort u[8]; uint4 v; } hu, lu;
#pragma unroll
        for (int j = 0; j < 8; ++j) split_bf(ts[l8 + j][c], hu.u[j], lu.u[j]);
        const size_t rb = ((size_t)b * C_ + c) * E_ + e0 + l8;
        *(uint4*)&xh[rb] = hu.v;
        *(uint4*)&xl[rb] = lu.v;
    }
}

// ---------------------------------------------------------------------------
// Pipelined split-bf16 MFMA GEMM, v2 (T3/T4/T5 with round-7 defects fixed).
// Block tile 128(o) x 256(c), BK=32, 8 waves (2x4), wave-tile 64x64, 3-term.
// LDS: 2 buffers x 48KB {Ah 8K | Al 8K | Bh 16K | Bl 16K}. Swizzle for 64B
// rows: slot c' = c ^ ((r>>1)&3) (2-way max = free). Counted vmcnt(6) per
// half-tile; frag-register double-buffer; 16 ds_read interleaved with 48
// MFMA per region; stage into just-freed buffer. Lane-contiguous epilogues.
// TRANS=1: operand-swapped MFMA (D-col = o) -> transposed split q/k stores
//          (z = bx>>2 selects q vs k; M=1024, NB=8).
// TRANS=0, FOUT=0: v natural hi-only (NB=4).  FOUT=1: fp32+selu out (NB=4).
// ---------------------------------------------------------------------------
template<int TRANS, int FOUT>
__global__ __launch_bounds__(512, 2) void gemm8p_kernel(
    const ushort* __restrict__ Wh, const ushort* __restrict__ Wl,
    const ushort* __restrict__ Bh, const ushort* __restrict__ Bl,
    ushort* __restrict__ o0h, ushort* __restrict__ o0l,
    ushort* __restrict__ o1h, ushort* __restrict__ o1l,
    float* __restrict__ fout, int NB)
{
    __shared__ ushort lds[2 * 24576];   // 96 KB

    // T1 bijective XCD remap (nwg % 8 == 0 in all modes)
    const int nwg = NB * 64;
    const int wI = blockIdx.x + NB * blockIdx.y;
    const int li = (wI & 7) * (nwg >> 3) + (wI >> 3);
    const int bx = li % NB, bgrp = li / NB;

    const int tid = threadIdx.x, wid = tid >> 6, lane = tid & 63;
    const int o0 = bx * 128;
    const int wr = wid >> 2, wc = wid & 3, l15 = lane & 15;

    // ---- stage precompute: 6 gll16 per thread per K-tile (48 total = 48KB)
    const char* sp[6];
    size_t so[6];
    int lo_[6];
#pragma unroll
    for (int q = 0; q < 6; ++q) {
        const int g = wid * 6 + q;
        int stream, inst;
        if (g < 8)       { stream = 0; inst = g; }
        else if (g < 16) { stream = 1; inst = g - 8; }
        else if (g < 32) { stream = 2; inst = g - 16; }
        else             { stream = 3; inst = g - 32; }
        const int rowbase = (stream < 2) ? (o0 + inst * 16)
                                         : (bgrp * 256 + inst * 16);
        sp[q] = (stream == 0) ? (const char*)Wh : (stream == 1) ? (const char*)Wl
              : (stream == 2) ? (const char*)Bh : (const char*)Bl;
        // source chunk pre-swizzled: (lane&3) ^ ((lane>>3)&3)  [= (row>>1)&3]
        so[q] = (size_t)(rowbase + (lane >> 2)) * (E_ * 2) +
                (size_t)(((lane & 3) ^ ((lane >> 3) & 3)) * 16);
        lo_[q] = ((stream == 0) ? 0 : (stream == 1) ? 4096 :
                  (stream == 2) ? 8192 : 16384) + inst * 512;   // ushort units
    }

    // ---- frag read byte offsets within a 48KB buffer (swizzled k-slot)
    const int koff = (((lane >> 4) ^ ((l15 >> 1) & 3)) << 4);
    int aoff[4], boff[4];
#pragma unroll
    for (int m = 0; m < 4; ++m) aoff[m] = (wr * 64 + m * 16 + l15) * 64 + koff;
#pragma unroll
    for (int n = 0; n < 4; ++n) boff[n] = 16384 + (wc * 64 + n * 16 + l15) * 64 + koff;

    f32x4 acc[4][4];
#pragma unroll
    for (int m = 0; m < 4; ++m)
#pragma unroll
        for (int n = 0; n < 4; ++n) acc[m][n] = (f32x4)0.0f;

    bf16x8 Aah[4], Aal[4], Abh[4], Abl[4];
    bf16x8 Bah[4], Bal[4], Bbh[4], Bbl[4];

#define STAGE(T, BUF) do { _Pragma("unroll") \
    for (int q = 0; q < 6; ++q) \
        gll16(sp[q] + so[q] + (size_t)(T) * 64, &lds[(BUF) * 24576 + lo_[q]]); \
    } while (0)

#define READF(P, BUF) do { const char* bb_ = (const char*)lds + (BUF) * 49152; \
    _Pragma("unroll") for (int m_ = 0; m_ < 4; ++m_) { \
        P##ah[m_] = *(const bf16x8*)(bb_ + aoff[m_]); \
        P##al[m_] = *(const bf16x8*)(bb_ + 8192 + aoff[m_]); } \
    _Pragma("unroll") for (int n_ = 0; n_ < 4; ++n_) { \
        P##bh[n_] = *(const bf16x8*)(bb_ + boff[n_]); \
        P##bl[n_] = *(const bf16x8*)(bb_ + 16384 + boff[n_]); } } while (0)

#define MFMA48(P) do { _Pragma("unroll") \
    for (int m_ = 0; m_ < 4; ++m_) { _Pragma("unroll") \
        for (int n_ = 0; n_ < 4; ++n_) { \
            if (TRANS) { \
                acc[n_][m_] = __builtin_amdgcn_mfma_f32_16x16x32_bf16(P##bh[n_], P##ah[m_], acc[n_][m_], 0, 0, 0); \
                acc[n_][m_] = __builtin_amdgcn_mfma_f32_16x16x32_bf16(P##bh[n_], P##al[m_], acc[n_][m_], 0, 0, 0); \
                acc[n_][m_] = __builtin_amdgcn_mfma_f32_16x16x32_bf16(P##bl[n_], P##ah[m_], acc[n_][m_], 0, 0, 0); \
            } else { \
                acc[m_][n_] = __builtin_amdgcn_mfma_f32_16x16x32_bf16(P##ah[m_], P##bh[n_], acc[m_][n_], 0, 0, 0); \
                acc[m_][n_] = __builtin_amdgcn_mfma_f32_16x16x32_bf16(P##ah[m_], P##bl[n_], acc[m_][n_], 0, 0, 0); \
                acc[m_][n_] = __builtin_amdgcn_mfma_f32_16x16x32_bf16(P##al[m_], P##bh[n_], acc[m_][n_], 0, 0, 0); \
            } } } } while (0)

#define WAITVM6 do { asm volatile("s_waitcnt vmcnt(6)" ::: "memory"); \
    __builtin_amdgcn_sched_barrier(0); } while (0)
#define WAITLG0 do { asm volatile("s_waitcnt lgkmcnt(0)" ::: "memory"); \
    __builtin_amdgcn_sched_barrier(0); } while (0)

    // ---- prologue: tiles 0,1 staged; frags of tile 0 into reg set A
    STAGE(0, 0);
    STAGE(1, 1);                      // 12 outstanding
    WAITVM6;                          // tile 0 landed (6 in flight)
    __builtin_amdgcn_s_barrier();
    READF(A, 0);
    WAITLG0;
    __builtin_amdgcn_s_barrier();     // buf0 free
    STAGE(2, 0);                      // 12 outstanding

    for (int tt = 0; tt < 16; tt += 2) {
        // even half: compute tile tt (set A); read tile tt+1 frags (set B)
        WAITVM6;                      // tile tt+1 landed
        __builtin_amdgcn_s_barrier();
        __builtin_amdgcn_s_setprio(1);
        READF(B, 1);
        MFMA48(A);
        __builtin_amdgcn_s_setprio(0);
        WAITLG0;
        __builtin_amdgcn_s_barrier(); // buf1 free
        STAGE((tt + 3 > 15) ? 15 : tt + 3, 1);

        // odd half: compute tile tt+1 (set B); read tile tt+2 frags (set A)
        WAITVM6;                      // tile tt+2 landed (or dummy)
        __builtin_amdgcn_s_barrier();
        __builtin_amdgcn_s_setprio(1);
        if (tt < 14) READF(A, 0);
        MFMA48(B);
        __builtin_amdgcn_s_setprio(0);
        WAITLG0;
        __builtin_amdgcn_s_barrier(); // buf0 free
        STAGE((tt + 4 > 15) ? 15 : tt + 4, 0);
    }
    asm volatile("s_waitcnt vmcnt(0)" ::: "memory");   // drain dummy stages

    // ---- epilogue (lane-contiguous 32B runs in all modes)
    const int lr4 = (lane >> 4) * 4;
    if (FOUT) {
        // fout[(b*E + o)*C + c], col(l15) = c
#pragma unroll
        for (int m = 0; m < 4; ++m)
#pragma unroll
            for (int n = 0; n < 4; ++n) {
                const int R = bgrp * 256 + wc * 64 + n * 16 + l15;   // b*C + c
                const int o = o0 + wr * 64 + m * 16 + lr4;
                const f32x4 a = acc[m][n];
                float* po = fout + ((size_t)(R >> 7) * E_ + o) * C_ + (R & 127);
#pragma unroll
                for (int j = 0; j < 4; ++j) po[(size_t)j * C_] = selu_f(a[j]);
            }
    } else if (TRANS) {
        // q/k transposed split: th[(b*C+c)*E + o], col(l15) = o (contiguous)
        const int z = bx >> 2;
        ushort* __restrict__ th = z ? o1h : o0h;
        ushort* __restrict__ tl = z ? o1l : o0l;
        const int oz = (bx & 3) * 128;
#pragma unroll
        for (int n = 0; n < 4; ++n)
#pragma unroll
            for (int m = 0; m < 4; ++m) {
                const int o = oz + wr * 64 + m * 16 + l15;
                const int Rb = bgrp * 256 + wc * 64 + n * 16 + lr4;
                const f32x4 a = acc[n][m];
#pragma unroll
                for (int j = 0; j < 4; ++j) {
                    ushort hi, lo;
                    split_bf(selu_f(a[j]), hi, lo);
                    const size_t idx = (size_t)(Rb + j) * E_ + o;
                    th[idx] = hi;
                    tl[idx] = lo;
                }
            }
    } else {
        // v natural hi-only: vhp[(b*E + o)*C + c], col(l15) = c
#pragma unroll
        for (int m = 0; m < 4; ++m)
#pragma unroll
            for (int n = 0; n < 4; ++n) {
                const int R = bgrp * 256 + wc * 64 + n * 16 + l15;
                const int o = o0 + wr * 64 + m * 16 + lr4;
                const f32x4 a = acc[m][n];
#pragma unroll
                for (int j = 0; j < 4; ++j)
                    o0h[((size_t)(R >> 7) * E_ + o + j) * C_ + (R & 127)] =
                        f2bf(selu_f(a[j]));
            }
    }
#undef STAGE
#undef READF
#undef MFMA48
#undef WAITVM6
#undef WAITLG0
}

// ---------------------------------------------------------------------------
// MFMA attention, one block (4 waves) per (b,h). 80 KB LDS -> 2 blocks/CU.
// (unchanged — verified passing)
// ---------------------------------------------------------------------------
__global__ __launch_bounds__(256, 2) void attn_mfma_kernel(
    const ushort* __restrict__ qTh, const ushort* __restrict__ qTl,
    const ushort* __restrict__ kTh, const ushort* __restrict__ kTl,
    const ushort* __restrict__ vh,  const float* __restrict__ combT,
    ushort* __restrict__ aTh, ushort* __restrict__ aTl)
{
    const int b = blockIdx.x, h = blockIdx.y;
    __shared__ ushort lds[40960];
    ushort* sQh = lds;
    ushort* sQl = lds + 8192;
    ushort* sKh = lds + 16384;
    ushort* sKl = lds + 24576;
    ushort* sV  = lds + 32768;
    ushort* sPh = lds;
    ushort* sPl = lds + 16384;

    const int tid = threadIdx.x, wid = tid >> 6, lane = tid & 63;

    {
        const size_t gq = (size_t)b * C_ * E_ + h * D_;
        const int rsub = lane >> 3, chunk = lane & 7;
#pragma unroll
        for (int t = 0; t < 4; ++t) {
            const int inst = wid * 4 + t;
            const int row = inst * 8 + rsub;
            const size_t goff = (gq + (size_t)row * E_) * 2 +
                                (size_t)(chunk ^ (row & 7)) * 16;
            gll16((const char*)qTh + goff, &sQh[inst * 512]);
            gll16((const char*)qTl + goff, &sQl[inst * 512]);
            gll16((const char*)kTh + goff, &sKh[inst * 512]);
            gll16((const char*)kTl + goff, &sKl[inst * 512]);
        }
        const size_t gv = ((size_t)b * E_ + h * D_) * C_;
        const int vr = lane >> 4, vchunk = lane & 15;
#pragma unroll
        for (int t = 0; t < 4; ++t) {
            const int inst = wid * 4 + t;
            const int row = inst * 4 + vr;
            const size_t goff = (gv + (size_t)row * C_) * 2 +
                                (size_t)(vchunk ^ (row & 7)) * 16;
            gll16((const char*)vh + goff, &sV[inst * 512]);
        }
    }
    __syncthreads();

    const int i0 = wid * 32;
    const int l15 = lane & 15;

    f32x4 acc[2][8];
#pragma unroll
    for (int m = 0; m < 2; ++m)
#pragma unroll
        for (int n = 0; n < 8; ++n) acc[m][n] = (f32x4)0.0f;

#pragma unroll
    for (int kk = 0; kk < 2; ++kk) {
        const int kbyte = kk * 64 + (lane >> 4) * 16;
        bf16x8 qhf[2], qlf[2];
#pragma unroll
        for (int m = 0; m < 2; ++m) {
            const int r = i0 + m * 16 + l15;
            const int byt = r * 128 + (kbyte ^ ((r & 7) << 4));
            qhf[m] = *(const bf16x8*)((const char*)sQh + byt);
            qlf[m] = *(const bf16x8*)((const char*)sQl + byt);
        }
#pragma unroll
        for (int n = 0; n < 8; ++n) {
            const int r = n * 16 + l15;
            const int byt = r * 128 + (kbyte ^ ((r & 7) << 4));
            const bf16x8 khf = *(const bf16x8*)((const char*)sKh + byt);
            const bf16x8 klf = *(const bf16x8*)((const char*)sKl + byt);
#pragma unroll
            for (int m = 0; m < 2; ++m) {
                acc[m][n] = __builtin_amdgcn_mfma_f32_16x16x32_bf16(
                    qhf[m], khf, acc[m][n], 0, 0, 0);
                acc[m][n] = __builtin_amdgcn_mfma_f32_16x16x32_bf16(
                    qhf[m], klf, acc[m][n], 0, 0, 0);
                acc[m][n] = __builtin_amdgcn_mfma_f32_16x16x32_bf16(
                    qlf[m], khf, acc[m][n], 0, 0, 0);
            }
        }
    }

#pragma unroll
    for (int m = 0; m < 2; ++m)
#pragma unroll
        for (int n = 0; n < 8; ++n) {
            const int jcol = n * 16 + l15;
            const float4 cb = *(const float4*)&combT[
                ((size_t)h * C_ + jcol) * C_ + i0 + m * 16 + (lane >> 4) * 4];
            acc[m][n][0] = fmaf(acc[m][n][0], 0.125f, cb.x);
            acc[m][n][1] = fmaf(acc[m][n][1], 0.125f, cb.y);
            acc[m][n][2] = fmaf(acc[m][n][2], 0.125f, cb.z);
            acc[m][n][3] = fmaf(acc[m][n][3], 0.125f, cb.w);
        }

#pragma unroll
    for (int m = 0; m < 2; ++m)
#pragma unroll
        for (int jj = 0; jj < 4; ++jj) {
            float mx = -INFINITY;
#pragma unroll
            for (int n = 0; n < 8; ++n) mx = fmaxf(mx, acc[m][n][jj]);
#pragma unroll
            for (int off = 1; off < 16; off <<= 1)
                mx = fmaxf(mx, __shfl_xor(mx, off));
            float sum = 0.0f;
#pragma unroll
            for (int n = 0; n < 8; ++n) {
                const float e = __expf(acc[m][n][jj] - mx);
                acc[m][n][jj] = e;
                sum += e;
            }
#pragma unroll
            for (int off = 1; off < 16; off <<= 1) sum += __shfl_xor(sum, off);
            const float inv = 1.0f / sum;
#pragma unroll
            for (int n = 0; n < 8; ++n) acc[m][n][jj] *= inv;
        }

    __syncthreads();
#pragma unroll
    for (int m = 0; m < 2; ++m)
#pragma unroll
        for (int n = 0; n < 8; ++n)
#pragma unroll
            for (int jj = 0; jj < 4; ++jj) {
                const int i = i0 + m * 16 + (lane >> 4) * 4 + jj;
                const int col = n * 16 + l15;
                const int byt = i * 256 + ((col * 2) ^ ((i & 7) << 4));
                ushort hi, lo;
                split_bf(acc[m][n][jj], hi, lo);
                *(ushort*)((char*)sPh + byt) = hi;
                *(ushort*)((char*)sPl + byt) = lo;
            }
    __syncthreads();

    f32x4 acc2[2][4];
#pragma unroll
    for (int m = 0; m < 2; ++m)
#pragma unroll
        for (int n = 0; n < 4; ++n) acc2[m][n] = (f32x4)0.0f;

#pragma unroll
    for (int ks = 0; ks < 4; ++ks) {
        const int kbyte = ks * 64 + (lane >> 4) * 16;
        bf16x8 ph[2], pl[2];
#pragma unroll
        for (int m = 0; m < 2; ++m) {
            const int r = i0 + m * 16 + l15;
            const int byt = r * 256 + (kbyte ^ ((r & 7) << 4));
            ph[m] = *(const bf16x8*)((const char*)sPh + byt);
            pl[m] = *(const bf16x8*)((const char*)sPl + byt);
        }
#pragma unroll
        for (int n = 0; n < 4; ++n) {
            const int d = n * 16 + l15;
            const int byt = d * 256 + (kbyte ^ ((d & 7) << 4));
            const bf16x8 vb = *(const bf16x8*)((const char*)sV + byt);
#pragma unroll
            for (int m = 0; m < 2; ++m) {
                acc2[m][n] = __builtin_amdgcn_mfma_f32_16x16x32_bf16(
                    ph[m], vb, acc2[m][n], 0, 0, 0);
                acc2[m][n] = __builtin_amdgcn_mfma_f32_16x16x32_bf16(
                    pl[m], vb, acc2[m][n], 0, 0, 0);
            }
        }
    }

#pragma unroll
    for (int m = 0; m < 2; ++m)
#pragma unroll
        for (int n = 0; n < 4; ++n)
#pragma unroll
            for (int jj = 0; jj < 4; ++jj) {
                const int i = i0 + m * 16 + (lane >> 4) * 4 + jj;
                const int dcol = n * 16 + l15;
                ushort hi, lo;
                split_bf(acc2[m][n][jj], hi, lo);
                const size_t idx = ((size_t)b * C_ + i) * E_ + h * D_ + dcol;
                aTh[idx] = hi;
                aTl[idx] = lo;
            }
}

// ---------------------------------------------------------------------------
extern "C" void kernel_launch(void* const* d_in, const int* in_sizes, int n_in,
                              void* d_out, int out_size, void* d_ws, size_t ws_size,
                              hipStream_t stream) {
    const float* x        = (const float*)d_in[0];
    const float* wq       = (const float*)d_in[1];
    const float* wk       = (const float*)d_in[2];
    const float* wv       = (const float*)d_in[3];
    const float* wo       = (const float*)d_in[4];
    const float* dir_vec  = (const float*)d_in[5];
    const float* attn_b   = (const float*)d_in[6];
    const float* disp     = (const float*)d_in[7];
    const unsigned char* knn = (const unsigned char*)d_in[8];
    float* out = (float*)d_out;

    char* ws = (char*)d_ws;
    size_t off = 0;
    ushort* qTh = (ushort*)(ws + off); off += BEC_ * 2;
    ushort* qTl = (ushort*)(ws + off); off += BEC_ * 2;
    ushort* kTh = (ushort*)(ws + off); off += BEC_ * 2;
    ushort* kTl = (ushort*)(ws + off); off += BEC_ * 2;
    ushort* vbuf = (ushort*)(ws + off); off += BEC_ * 2;
    ushort* xTh = (ushort*)(ws + off); off += BEC_ * 2;   // reused as attnT hi
    ushort* xTl = (ushort*)(ws + off); off += BEC_ * 2;   // reused as attnT lo
    ushort* wh  = (ushort*)(ws + off); off += (size_t)4 * E_ * E_ * 2;
    ushort* wl  = (ushort*)(ws + off); off += (size_t)4 * E_ * E_ * 2;
    float* combT = (float*)(ws + off); off += (size_t)H_ * C_ * C_ * sizeof(float);
    int* flag = (int*)(ws + off);

    detect_mask_kernel<<<1, 256, 0, stream>>>(knn, flag);
    bias_prep_kernel<<<dim3(C_, H_), 128, 0, stream>>>(dir_vec, attn_b, disp, knn,
                                                       flag, combT);
    wsplit_kernel<<<dim3(128, 4), 256, 0, stream>>>(wq, wk, wv, wo, wh, wl);
    xsplit_kernel<<<dim3(8, B_), 256, 0, stream>>>(x, xTh, xTl);

    const size_t WSZ = (size_t)E_ * E_;
    // q+k (M=1024, operand-swapped -> transposed split stores)
    gemm8p_kernel<1, 0><<<dim3(8, 64), 512, 0, stream>>>(
        wh, wl, xTh, xTl, qTh, qTl, kTh, kTl, nullptr, 8);
    // v (natural hi-only)
    gemm8p_kernel<0, 0><<<dim3(4, 64), 512, 0, stream>>>(
        wh + 2 * WSZ, wl + 2 * WSZ, xTh, xTl,
        vbuf, nullptr, nullptr, nullptr, nullptr, 4);
    // MFMA attention -> attnT over xT buffers
    attn_mfma_kernel<<<dim3(B_, H_), 256, 0, stream>>>(
        qTh, qTl, kTh, kTl, vbuf, combT, xTh, xTl);
    // output projection -> d_out
    gemm8p_kernel<0, 1><<<dim3(4, 64), 512, 0, stream>>>(
        wh + 3 * WSZ, wl + 3 * WSZ, xTh, xTl,
        nullptr, nullptr, nullptr, nullptr, out, 4);
}